// Round 9
// baseline (449.418 us; speedup 1.0000x reference)
//
#include <hip/hip_runtime.h>
#include <hip/hip_bf16.h>
#include <stdint.h>

// MegaNeRF fused MoE-MLP for MI355X (gfx950).  Round 9.
// E=8 experts, MLP 90->256->256->256->4, N=131072 points, inverse-distance gating.
//
// Round-9: r8's conflict-free swapped-operand layout (h'^T = W^T h^T, D packs
// to one b64 store, reads lane-linear b128) + the register fix r8 lacked:
// 16 waves (1024 thr) with per-wave tile 64ch x 32pt -> acc[4][2] = 32 regs,
// total ~92 <= 128 forced by block size -> 4 waves/SIMD, NO spill (r8 spilled
// ~760 MB to HBM).  Plus ping-pong hA/hB (132 KB LDS): 1 barrier/layer.

#define NE    8
#define FIN   90
#define HD    256
#define NOUT  4
#define XC    93          // 3 + FIN columns in x

#define MT        128     // points per block
#define NTHREADS  1024    // 16 waves: wch(4) x wpt(4)

#define KQ1   3           // ceil(90/32) -> K padded to 96
#define KQH   8           // 256/32
#define NBH   16          // 256/16

#define W1_ELEMS (NE*NBH*KQ1*512)   // 196608
#define W2_ELEMS (NE*NBH*KQH*512)   // 524288
#define WO_ELEMS (NE*KQH*512)       // 32768  (OUT padded 4->16)
#define WTOT     (W1_ELEMS + 2*W2_ELEMS + WO_ELEMS)   // 1277952 elems

typedef __attribute__((ext_vector_type(8))) short bf16x8;
typedef __attribute__((ext_vector_type(4))) short bf16x4;
typedef __attribute__((ext_vector_type(4))) float f32x4;

__device__ __forceinline__ unsigned short f2bf(float f) {   // cold path only
  union { float f; uint32_t u; } v; v.f = f;
  v.u += 0x7fffu + ((v.u >> 16) & 1u);   // RNE
  return (unsigned short)(v.u >> 16);
}

__device__ __forceinline__ short relu_bf(float f) {         // hot epilogue
  __hip_bfloat16 t = __float2bfloat16(fmaxf(f, 0.f));
  return __builtin_bit_cast(short, t);
}

// ---------------------------------------------------------------------------
// Weight conversion (IDENTICAL to r1-r6/r8, verified): f32 [e][k][n] -> bf16
// fragments [frag][lane][8], frag = (e*NBH + nb)*KQ + kq,
// elem (lane,j) = W[k = kq*32+(lane>>4)*8+j][n = nb*16+(lane&15)].
// ---------------------------------------------------------------------------
__global__ __launch_bounds__(256)
void convert_weights(const float* __restrict__ W1, const float* __restrict__ W2,
                     const float* __restrict__ W3, const float* __restrict__ Wo,
                     unsigned short* __restrict__ ws) {
  int idx = blockIdx.x * 256 + threadIdx.x;
  int j = idx & 7;
  int lane = (idx >> 3) & 63;
  int n16 = lane & 15;
  int kof = ((lane >> 4) << 3) + j;
  if (idx < W1_ELEMS) {
    int f = idx >> 9;
    int kq = f % KQ1; f /= KQ1;
    int nb = f % NBH; int e = f / NBH;
    int n = nb*16 + n16, k = kq*32 + kof;
    float v = (k < FIN) ? W1[(e*FIN + k)*HD + n] : 0.f;
    ws[idx] = f2bf(v);
  } else if (idx < W1_ELEMS + 2*W2_ELEMS) {
    int t = idx - W1_ELEMS;
    const float* W = (t < W2_ELEMS) ? W2 : W3;
    int u = (t < W2_ELEMS) ? t : (t - W2_ELEMS);
    int f = u >> 9;
    int kq = f % KQH; f /= KQH;
    int nb = f % NBH; int e = f / NBH;
    int n = nb*16 + n16, k = kq*32 + kof;
    ws[idx] = f2bf(W[(e*HD + k)*HD + n]);
  } else if (idx < WTOT) {
    int t = idx - (W1_ELEMS + 2*W2_ELEMS);
    int f = t >> 9;
    int kq = f % KQH; int e = f / KQH;
    int k = kq*32 + kof;
    float v = (n16 < NOUT) ? Wo[(e*HD + k)*NOUT + n16] : 0.f;
    ws[idx] = f2bf(v);
  }
}

// ---------------------------------------------------------------------------
// X conversion (IDENTICAL to r5/r6/r8): f32 x[:,3:] -> bf16 fragments, frag
// f = r16*KQ1 + kq, elem (lane,j) = X[r16*16+(lane&15)][kq*32+(lane>>4)*8+j].
// Consumed as the B-operand (lane&15 = point col).
// ---------------------------------------------------------------------------
__global__ __launch_bounds__(256)
void convert_x(const float* __restrict__ x, unsigned short* __restrict__ xs, int nfrag) {
  int idx = blockIdx.x * 256 + threadIdx.x;
  if (idx >= nfrag * 512) return;
  int j = idx & 7;
  int lane = (idx >> 3) & 63;
  int f = idx >> 9;
  int kq = f % KQ1;
  int r16 = f / KQ1;
  int row = r16*16 + (lane & 15);
  int k = kq*32 + ((lane >> 4) << 3) + j;
  float v = (k < FIN) ? x[(size_t)row*XC + 3 + k] : 0.f;
  xs[idx] = f2bf(v);
}

// ---------------------------------------------------------------------------
// Epilogue (r8 algebra, wpt now spans 2 mtiles): relu + pack 4 consecutive
// channels (D regs) -> one b64 store into dst's B-frag layout.
// D: point m = wpt*32+pf*16+l15 (col), channel c = wch*64+cf*16+l4*4+j (row).
// elem = (m>>4)*4096 + (c>>5)*512 + ((m&15)+16*((c&31)>>3))*8 + (c&7).
// Thread base: wpt*8192 + wch*1024 + l15*8 + (l4>>1)*128 + (l4&1)*4;
// offsets pf*4096 + (cf>>1)*512 + (cf&1)*256.  4 bank phases -> conflict-free.
// ---------------------------------------------------------------------------
__device__ __forceinline__ void store_hB(f32x4 (&acc)[4][2], unsigned short* dst,
                                         int wch, int wpt, int l15, int l4) {
  unsigned short* base = dst + wpt*8192 + wch*1024 + l15*8 + (l4>>1)*128 + (l4&1)*4;
#pragma unroll
  for (int cf = 0; cf < 4; ++cf)
#pragma unroll
    for (int pf = 0; pf < 2; ++pf) {
      bf16x4 s;
      s.x = relu_bf(acc[cf][pf][0]);
      s.y = relu_bf(acc[cf][pf][1]);
      s.z = relu_bf(acc[cf][pf][2]);
      s.w = relu_bf(acc[cf][pf][3]);
      *reinterpret_cast<bf16x4*>(base + pf*4096 + (cf>>1)*512 + (cf&1)*256) = s;
    }
}

// One hidden layer src -> dst (ping-pong; caller places ONE barrier after).
__device__ __forceinline__ void layerH(const unsigned short* src, unsigned short* dst,
                                       const unsigned short* __restrict__ fw,
                                       const float* __restrict__ bias,
                                       int wch, int wpt, int l15, int l4, int lane) {
  f32x4 acc[4][2];   // [cf][pf]
#pragma unroll
  for (int cf = 0; cf < 4; ++cf) {
    f32x4 bv = *reinterpret_cast<const f32x4*>(&bias[wch*64 + cf*16 + l4*4]);
    acc[cf][0] = bv; acc[cf][1] = bv;
  }

  const unsigned short* rb = src + wpt*8192 + lane*8;
#pragma unroll
  for (int kq = 0; kq < KQH; ++kq) {
    bf16x8 aw[4];
#pragma unroll
    for (int cf = 0; cf < 4; ++cf)
      aw[cf] = *(const bf16x8*)(fw + ((((wch*4 + cf)*KQH) + kq) << 9) + lane*8);
#pragma unroll
    for (int pf = 0; pf < 2; ++pf) {
      bf16x8 bh = *(const bf16x8*)(rb + pf*4096 + kq*512);
#pragma unroll
      for (int cf = 0; cf < 4; ++cf)
        acc[cf][pf] = __builtin_amdgcn_mfma_f32_16x16x32_bf16(aw[cf], bh, acc[cf][pf], 0, 0, 0);
    }
  }
  store_hB(acc, dst, wch, wpt, l15, l4);
}

template<bool XSTAGED>
__global__ __launch_bounds__(NTHREADS)
void meganerf_fused(const float* __restrict__ x, const float* __restrict__ cent,
                    const float* __restrict__ b1, const float* __restrict__ b2,
                    const float* __restrict__ b3, const float* __restrict__ bo,
                    const unsigned short* __restrict__ wf,
                    const unsigned short* __restrict__ xs,
                    float* __restrict__ out) {
  __shared__ unsigned short hA[8 * KQH * 512];  // 65536 B: [mtile][kq][lane][8]
  __shared__ unsigned short hBuf[8 * KQH * 512];// 65536 B (ping-pong partner)
  __shared__ float wcl[MT * NE];                // 4096 B   -> total 135168 B

  const int tid = threadIdx.x;
  const int lane = tid & 63;
  const int wv = tid >> 6;      // 0..15
  const int wch = wv >> 2;      // channel group 0..3 (64 channels each)
  const int wpt = wv & 3;       // point group 0..3 (32 points each)
  const int l15 = lane & 15, l4 = lane >> 4;
  const int row0 = blockIdx.x * MT;

  // --- cluster weights (strict IEEE f32, no contraction: must bit-match np) ---
  if (tid < MT) {
    const int p = row0 + tid;
    float px = x[p*XC + 1], py = x[p*XC + 2];
    float d[NE]; float mind = 3.4e38f;
#pragma unroll
    for (int e = 0; e < NE; ++e) {
      float dx = px - cent[e*3 + 1];
      float dy = py - cent[e*3 + 2];
      d[e] = __fsqrt_rn(__fmul_rn(dx, dx) + __fmul_rn(dy, dy));
      mind = fminf(mind, d[e]);
    }
    float m = 1.5f * mind, s = 0.f, inv[NE];
#pragma unroll
    for (int e = 0; e < NE; ++e) {
      float iv = (d[e] > m) ? 0.f : 1.f / (d[e] + 1e-8f);
      inv[e] = iv; s += iv;
    }
#pragma unroll
    for (int e = 0; e < NE; ++e) wcl[tid*NE + e] = inv[e] / s;
  }
  __syncthreads();

  const unsigned short* fw1 = wf;
  const unsigned short* fw2 = wf + W1_ELEMS;
  const unsigned short* fw3 = fw2 + W2_ELEMS;
  const unsigned short* fwo = fw3 + W2_ELEMS;
  const unsigned short* xsb = xs + ((size_t)(blockIdx.x*8 + wpt*2)*KQ1)*512 + lane*8;

  float og[NOUT] = {0.f, 0.f, 0.f, 0.f};   // gated outputs (waves 0-7, l4==0)

  for (int e = 0; e < NE; ++e) {
    // ---- layer 1: h^T = relu(W1^T X^T + b1) -> hA ----
    {
      f32x4 acc[4][2];
#pragma unroll
      for (int cf = 0; cf < 4; ++cf) {
        f32x4 bv = *reinterpret_cast<const f32x4*>(&b1[e*HD + wch*64 + cf*16 + l4*4]);
        acc[cf][0] = bv; acc[cf][1] = bv;
      }
#pragma unroll
      for (int kq = 0; kq < KQ1; ++kq) {
        bf16x8 aw[4];
#pragma unroll
        for (int cf = 0; cf < 4; ++cf)
          aw[cf] = *(const bf16x8*)(fw1 + (((e*NBH + wch*4 + cf)*KQ1 + kq) << 9) + lane*8);
#pragma unroll
        for (int pf = 0; pf < 2; ++pf) {
          bf16x8 bx;
          if constexpr (XSTAGED) {
            bx = *(const bf16x8*)(xsb + (pf*KQ1 + kq)*512);
          } else {
            const int row = row0 + (wpt*2 + pf)*16 + l15;
            const int kb = kq*32 + l4*8;
            const float* src = x + (size_t)row*XC + 3;
#pragma unroll
            for (int j = 0; j < 8; ++j)
              bx[j] = (short)((kb + j < FIN) ? f2bf(src[kb + j]) : (unsigned short)0);
          }
#pragma unroll
          for (int cf = 0; cf < 4; ++cf)
            acc[cf][pf] = __builtin_amdgcn_mfma_f32_16x16x32_bf16(aw[cf], bx, acc[cf][pf], 0, 0, 0);
        }
      }
      store_hB(acc, hA, wch, wpt, l15, l4);   // hA free: end-of-expert barrier
    }
    __syncthreads();

    // ---- layer 2: hA -> hBuf ----
    layerH(hA, hBuf, fw2 + (e << 16), b2 + e*HD, wch, wpt, l15, l4, lane);
    __syncthreads();
    // ---- layer 3: hBuf -> hA ----
    layerH(hBuf, hA, fw3 + (e << 16), b3 + e*HD, wch, wpt, l15, l4, lane);
    __syncthreads();

    // ---- layer 4: out^T = Wo^T h^T; waves 0-7 own one 16-pt mtile each ----
    if (wv < 8) {
      f32x4 acc = {0.f, 0.f, 0.f, 0.f};
#pragma unroll
      for (int kq = 0; kq < KQH; ++kq) {
        bf16x8 aw = *(const bf16x8*)(fwo + ((e*KQH + kq) << 9) + lane*8);
        bf16x8 bh = *(const bf16x8*)(hA + wv*4096 + kq*512 + lane*8);
        acc = __builtin_amdgcn_mfma_f32_16x16x32_bf16(aw, bh, acc, 0, 0, 0);
      }
      // D: col=l15 (point within mtile wv), row=l4*4+j (out channel; 0..3 real)
      if (l4 == 0) {
        float w = wcl[(wv*16 + l15)*NE + e];
#pragma unroll
        for (int j = 0; j < NOUT; ++j)
          og[j] += w * (acc[j] + bo[e*NOUT + j]);
      }
    }
    __syncthreads();   // L4 reads of hA done; next expert's L1 may rewrite hA
  }

  if (wv < 8 && l4 == 0) {
    f32x4 o = {og[0], og[1], og[2], og[3]};
    *reinterpret_cast<f32x4*>(&out[(size_t)(row0 + wv*16 + l15)*NOUT]) = o;
  }
}

extern "C" void kernel_launch(void* const* d_in, const int* in_sizes, int n_in,
                              void* d_out, int out_size, void* d_ws, size_t ws_size,
                              hipStream_t stream) {
  const float* x    = (const float*)d_in[0];
  const float* cent = (const float*)d_in[1];
  const float* W1   = (const float*)d_in[2];
  const float* b1   = (const float*)d_in[3];
  const float* W2   = (const float*)d_in[4];
  const float* b2   = (const float*)d_in[5];
  const float* W3   = (const float*)d_in[6];
  const float* b3   = (const float*)d_in[7];
  const float* Wo   = (const float*)d_in[8];
  const float* bo   = (const float*)d_in[9];
  float* out = (float*)d_out;
  unsigned short* wsb = (unsigned short*)d_ws;

  const int N = in_sizes[0] / XC;                 // 131072
  const int nfragX = (N/16) * KQ1;                // 24576 fragments
  const size_t wbytes = (size_t)WTOT * 2;         // 2,555,904
  const size_t xbytes = (size_t)nfragX * 512 * 2; // 25,165,824

  convert_weights<<<dim3((WTOT + 255) / 256), dim3(256), 0, stream>>>(W1, W2, W3, Wo, wsb);

  if (ws_size >= wbytes + xbytes) {
    unsigned short* xsb2 = wsb + WTOT;
    convert_x<<<dim3((nfragX*512 + 255) / 256), dim3(256), 0, stream>>>(x, xsb2, nfragX);
    meganerf_fused<true><<<dim3(N / MT), dim3(NTHREADS), 0, stream>>>(
        x, cent, b1, b2, b3, bo, wsb, xsb2, out);
  } else {
    meganerf_fused<false><<<dim3(N / MT), dim3(NTHREADS), 0, stream>>>(
        x, cent, b1, b2, b3, bo, wsb, wsb, out);
  }
}

// Round 10
// 371.494 us; speedup vs baseline: 1.2098x; 1.2098x over previous
//
#include <hip/hip_runtime.h>
#include <hip/hip_bf16.h>
#include <stdint.h>

// MegaNeRF fused MoE-MLP for MI355X (gfx950).  Round 10.
// E=8 experts, MLP 90->256->256->256->4, N=131072 points, inverse-distance gating.
//
// Round-10 vs r9 (449 us, MfmaUtil 32, VALUBusy 23, clean regs):
//  - wave tile 32ch x 64pt (wch 0..7, wpt 0..1): per-kq global aw loads 4->2,
//    L2 weight traffic halves; extra bh reads go to the roomier LDS pipe.
//  - weight fragments reordered [e][wch][kq][cf] -> each wave reads one
//    contiguous run; offsets are imm-foldable (cf*1KB, kq*2KB).
//  - readfirstlane-hoisted SGPR fragment bases: address math -> SALU.

#define NE    8
#define FIN   90
#define HD    256
#define NOUT  4
#define XC    93          // 3 + FIN columns in x

#define MT        128     // points per block
#define NTHREADS  1024    // 16 waves: wch(8) x wpt(2)

#define KQ1   3           // ceil(90/32) -> K padded to 96
#define KQH   8           // 256/32

#define W1_ELEMS (NE*8*KQ1*2*512)   // 196608
#define W2_ELEMS (NE*8*KQH*2*512)   // 524288
#define WO_ELEMS (NE*KQH*512)       // 32768  (OUT padded 4->16)
#define WTOT     (W1_ELEMS + 2*W2_ELEMS + WO_ELEMS)   // 1277952 elems

typedef __attribute__((ext_vector_type(8))) short bf16x8;
typedef __attribute__((ext_vector_type(4))) short bf16x4;
typedef __attribute__((ext_vector_type(4))) float f32x4;

__device__ __forceinline__ unsigned short f2bf(float f) {   // cold path only
  union { float f; uint32_t u; } v; v.f = f;
  v.u += 0x7fffu + ((v.u >> 16) & 1u);   // RNE
  return (unsigned short)(v.u >> 16);
}

__device__ __forceinline__ short relu_bf(float f) {         // hot epilogue
  __hip_bfloat16 t = __float2bfloat16(fmaxf(f, 0.f));
  return __builtin_bit_cast(short, t);
}

// wave-uniform pointer -> SGPR (HK technique: readfirstlane base hoisting)
__device__ __forceinline__ const unsigned short* rf_ptr(const unsigned short* p) {
  uint64_t u = (uint64_t)(uintptr_t)p;
  uint32_t lo = __builtin_amdgcn_readfirstlane((uint32_t)u);
  uint32_t hi = __builtin_amdgcn_readfirstlane((uint32_t)(u >> 32));
  return (const unsigned short*)(uintptr_t)(((uint64_t)hi << 32) | lo);
}

// ---------------------------------------------------------------------------
// Weight conversion: f32 [e][k][n] -> bf16 B-fragments [lane][8] ordered so a
// wave's per-layer stream is contiguous:
//   W1:     frag g = ((e*8 + wch)*3 + kq)*2 + cf
//   W2/W3:  frag g = ((e*8 + wch)*8 + kq)*2 + cf
//   Wo:     frag g = e*8 + kq
// elem (lane,j) = W[k = kq*32+(lane>>4)*8+j][n = wch*32 + cf*16 + (lane&15)].
// ---------------------------------------------------------------------------
__global__ __launch_bounds__(256)
void convert_weights(const float* __restrict__ W1, const float* __restrict__ W2,
                     const float* __restrict__ W3, const float* __restrict__ Wo,
                     unsigned short* __restrict__ ws) {
  int idx = blockIdx.x * 256 + threadIdx.x;
  int j = idx & 7;
  int lane = (idx >> 3) & 63;
  int n16 = lane & 15;
  int kof = ((lane >> 4) << 3) + j;
  if (idx < W1_ELEMS) {
    int g = idx >> 9;
    int cf = g & 1; int t = g >> 1;
    int kq = t % 3; t /= 3;
    int wch = t & 7; int e = t >> 3;
    int n = wch*32 + cf*16 + n16, k = kq*32 + kof;
    float v = (k < FIN) ? W1[(e*FIN + k)*HD + n] : 0.f;
    ws[idx] = f2bf(v);
  } else if (idx < W1_ELEMS + 2*W2_ELEMS) {
    int u = idx - W1_ELEMS;
    const float* W = (u < W2_ELEMS) ? W2 : W3;
    int uu = (u < W2_ELEMS) ? u : (u - W2_ELEMS);
    int g = uu >> 9;
    int cf = g & 1; int t = g >> 1;
    int kq = t & 7; t >>= 3;
    int wch = t & 7; int e = t >> 3;
    int n = wch*32 + cf*16 + n16, k = kq*32 + kof;
    ws[idx] = f2bf(W[(e*HD + k)*HD + n]);
  } else if (idx < WTOT) {
    int t = idx - (W1_ELEMS + 2*W2_ELEMS);
    int g = t >> 9;
    int kq = g & 7; int e = g >> 3;
    int k = kq*32 + kof;
    float v = (n16 < NOUT) ? Wo[(e*HD + k)*NOUT + n16] : 0.f;
    ws[idx] = f2bf(v);
  }
}

// ---------------------------------------------------------------------------
// X conversion (unchanged, verified r5-r9): frag f = r16*KQ1 + kq,
// elem (lane,j) = X[r16*16+(lane&15)][kq*32+(lane>>4)*8+j]  (0 beyond FIN).
// ---------------------------------------------------------------------------
__global__ __launch_bounds__(256)
void convert_x(const float* __restrict__ x, unsigned short* __restrict__ xs, int nfrag) {
  int idx = blockIdx.x * 256 + threadIdx.x;
  if (idx >= nfrag * 512) return;
  int j = idx & 7;
  int lane = (idx >> 3) & 63;
  int f = idx >> 9;
  int kq = f % KQ1;
  int r16 = f / KQ1;
  int row = r16*16 + (lane & 15);
  int k = kq*32 + ((lane >> 4) << 3) + j;
  float v = (k < FIN) ? x[(size_t)row*XC + 3 + k] : 0.f;
  xs[idx] = f2bf(v);
}

// ---------------------------------------------------------------------------
// Epilogue: relu + pack 4 consecutive channels -> one b64 store, B-frag layout.
// D: point m = wpt*64+pf*16+l15 (col), channel c = wch*32+cf*16+l4*4+j (row).
// elem = (m>>4)*4096 + (c>>5)*512 + ((m&15)+16*((c&31)>>3))*8 + (c&7)
//      = wpt*16384 + pf*4096 + wch*512 + l15*8 + cf*256 + (l4>>1)*128 + (l4&1)*4 + j.
// 64 lanes x 8B = 512B = 4 bank phases (minimum) -> conflict-free.
// ---------------------------------------------------------------------------
__device__ __forceinline__ void store_hB(f32x4 (&acc)[2][4], unsigned short* dst,
                                         int wch, int wpt, int l15, int l4) {
  unsigned short* base = dst + wpt*16384 + wch*512 + l15*8 + (l4>>1)*128 + (l4&1)*4;
#pragma unroll
  for (int cf = 0; cf < 2; ++cf)
#pragma unroll
    for (int pf = 0; pf < 4; ++pf) {
      bf16x4 s;
      s.x = relu_bf(acc[cf][pf][0]);
      s.y = relu_bf(acc[cf][pf][1]);
      s.z = relu_bf(acc[cf][pf][2]);
      s.w = relu_bf(acc[cf][pf][3]);
      *reinterpret_cast<bf16x4*>(base + pf*4096 + cf*256) = s;
    }
}

// One hidden layer src -> dst (ping-pong; caller places ONE barrier after).
// fw points at this (expert, wch) contiguous fragment run (16 frags).
__device__ __forceinline__ void layerH(const unsigned short* src, unsigned short* dst,
                                       const unsigned short* __restrict__ fw,
                                       const float* __restrict__ bias,
                                       int wch, int wpt, int l15, int l4, int lane) {
  f32x4 acc[2][4];   // [cf][pf]
#pragma unroll
  for (int cf = 0; cf < 2; ++cf) {
    f32x4 bv = *reinterpret_cast<const f32x4*>(&bias[wch*32 + cf*16 + l4*4]);
#pragma unroll
    for (int pf = 0; pf < 4; ++pf)
      acc[cf][pf] = bv;
  }

  const unsigned short* fwW = rf_ptr(fw) + lane*8;       // SGPR base + lane off
  const unsigned short* rb  = src + wpt*16384 + lane*8;  // LDS, imm offsets
#pragma unroll
  for (int kq = 0; kq < KQH; ++kq) {
    bf16x8 aw0 = *(const bf16x8*)(fwW + kq*1024);
    bf16x8 aw1 = *(const bf16x8*)(fwW + kq*1024 + 512);
#pragma unroll
    for (int pf = 0; pf < 4; ++pf) {
      bf16x8 bh = *(const bf16x8*)(rb + pf*4096 + kq*512);
      acc[0][pf] = __builtin_amdgcn_mfma_f32_16x16x32_bf16(aw0, bh, acc[0][pf], 0, 0, 0);
      acc[1][pf] = __builtin_amdgcn_mfma_f32_16x16x32_bf16(aw1, bh, acc[1][pf], 0, 0, 0);
    }
  }
  store_hB(acc, dst, wch, wpt, l15, l4);
}

template<bool XSTAGED>
__global__ __launch_bounds__(NTHREADS)
void meganerf_fused(const float* __restrict__ x, const float* __restrict__ cent,
                    const float* __restrict__ b1, const float* __restrict__ b2,
                    const float* __restrict__ b3, const float* __restrict__ bo,
                    const unsigned short* __restrict__ wf,
                    const unsigned short* __restrict__ xs,
                    float* __restrict__ out) {
  __shared__ unsigned short hA[8 * KQH * 512];  // 65536 B: [mtile][kq][lane][8]
  __shared__ unsigned short hBuf[8 * KQH * 512];// 65536 B (ping-pong partner)
  __shared__ float wcl[MT * NE];                // 4096 B   -> total 135168 B

  const int tid = threadIdx.x;
  const int lane = tid & 63;
  const int wv = tid >> 6;      // 0..15
  const int wch = wv >> 1;      // channel group 0..7 (32 channels each)
  const int wpt = wv & 1;       // point group 0..1 (64 points each)
  const int l15 = lane & 15, l4 = lane >> 4;
  const int row0 = blockIdx.x * MT;

  // --- cluster weights (strict IEEE f32, no contraction: must bit-match np) ---
  if (tid < MT) {
    const int p = row0 + tid;
    float px = x[p*XC + 1], py = x[p*XC + 2];
    float d[NE]; float mind = 3.4e38f;
#pragma unroll
    for (int e = 0; e < NE; ++e) {
      float dx = px - cent[e*3 + 1];
      float dy = py - cent[e*3 + 2];
      d[e] = __fsqrt_rn(__fmul_rn(dx, dx) + __fmul_rn(dy, dy));
      mind = fminf(mind, d[e]);
    }
    float m = 1.5f * mind, s = 0.f, inv[NE];
#pragma unroll
    for (int e = 0; e < NE; ++e) {
      float iv = (d[e] > m) ? 0.f : 1.f / (d[e] + 1e-8f);
      inv[e] = iv; s += iv;
    }
#pragma unroll
    for (int e = 0; e < NE; ++e) wcl[tid*NE + e] = inv[e] / s;
  }
  __syncthreads();

  const unsigned short* fw1 = wf;
  const unsigned short* fw2 = wf + W1_ELEMS;
  const unsigned short* fw3 = fw2 + W2_ELEMS;
  const unsigned short* fwo = fw3 + W2_ELEMS;
  // staged X base for this wave's four 16-row tiles (contiguous 12 frags)
  const unsigned short* xsb = xs + ((size_t)(blockIdx.x*8 + wpt*4)*KQ1)*512 + lane*8;

  float og[NOUT] = {0.f, 0.f, 0.f, 0.f};   // gated outputs (waves 0-7, l4==0)

  for (int e = 0; e < NE; ++e) {
    // ---- layer 1: h^T = relu(W1^T X^T + b1) -> hA ----
    {
      f32x4 acc[2][4];
#pragma unroll
      for (int cf = 0; cf < 2; ++cf) {
        f32x4 bv = *reinterpret_cast<const f32x4*>(&b1[e*HD + wch*32 + cf*16 + l4*4]);
#pragma unroll
        for (int pf = 0; pf < 4; ++pf)
          acc[cf][pf] = bv;
      }
      const unsigned short* fw1W = rf_ptr(fw1 + e*24576 + wch*3072) + lane*8;
#pragma unroll
      for (int kq = 0; kq < KQ1; ++kq) {
        bf16x8 aw0 = *(const bf16x8*)(fw1W + kq*1024);
        bf16x8 aw1 = *(const bf16x8*)(fw1W + kq*1024 + 512);
#pragma unroll
        for (int pf = 0; pf < 4; ++pf) {
          bf16x8 bx;
          if constexpr (XSTAGED) {
            bx = *(const bf16x8*)(xsb + (pf*KQ1 + kq)*512);
          } else {
            const int row = row0 + wpt*64 + pf*16 + l15;
            const int kb = kq*32 + l4*8;
            const float* src = x + (size_t)row*XC + 3;
#pragma unroll
            for (int j = 0; j < 8; ++j)
              bx[j] = (short)((kb + j < FIN) ? f2bf(src[kb + j]) : (unsigned short)0);
          }
          acc[0][pf] = __builtin_amdgcn_mfma_f32_16x16x32_bf16(aw0, bx, acc[0][pf], 0, 0, 0);
          acc[1][pf] = __builtin_amdgcn_mfma_f32_16x16x32_bf16(aw1, bx, acc[1][pf], 0, 0, 0);
        }
      }
      store_hB(acc, hA, wch, wpt, l15, l4);   // hA free: end-of-expert barrier
    }
    __syncthreads();

    // ---- layer 2: hA -> hBuf ----
    layerH(hA, hBuf, fw2 + e*65536 + wch*8192, b2 + e*HD, wch, wpt, l15, l4, lane);
    __syncthreads();
    // ---- layer 3: hBuf -> hA ----
    layerH(hBuf, hA, fw3 + e*65536 + wch*8192, b3 + e*HD, wch, wpt, l15, l4, lane);
    __syncthreads();

    // ---- layer 4: out^T = Wo^T h^T; waves 0-7 own one 16-pt mtile each ----
    if (wv < 8) {
      const unsigned short* fwoE = rf_ptr(fwo + e*4096) + lane*8;
      f32x4 acc = {0.f, 0.f, 0.f, 0.f};
#pragma unroll
      for (int kq = 0; kq < KQH; ++kq) {
        bf16x8 aw = *(const bf16x8*)(fwoE + kq*512);
        bf16x8 bh = *(const bf16x8*)(hA + wv*4096 + kq*512 + lane*8);
        acc = __builtin_amdgcn_mfma_f32_16x16x32_bf16(aw, bh, acc, 0, 0, 0);
      }
      // D: col=l15 (point within mtile wv), row=l4*4+j (out channel; 0..3 real)
      if (l4 == 0) {
        float w = wcl[(wv*16 + l15)*NE + e];
#pragma unroll
        for (int j = 0; j < NOUT; ++j)
          og[j] += w * (acc[j] + bo[e*NOUT + j]);
      }
    }
    __syncthreads();   // L4 reads of hA done; next expert's L1 may rewrite hA
  }

  if (wv < 8 && l4 == 0) {
    f32x4 o = {og[0], og[1], og[2], og[3]};
    *reinterpret_cast<f32x4*>(&out[(size_t)(row0 + wv*16 + l15)*NOUT]) = o;
  }
}

extern "C" void kernel_launch(void* const* d_in, const int* in_sizes, int n_in,
                              void* d_out, int out_size, void* d_ws, size_t ws_size,
                              hipStream_t stream) {
  const float* x    = (const float*)d_in[0];
  const float* cent = (const float*)d_in[1];
  const float* W1   = (const float*)d_in[2];
  const float* b1   = (const float*)d_in[3];
  const float* W2   = (const float*)d_in[4];
  const float* b2   = (const float*)d_in[5];
  const float* W3   = (const float*)d_in[6];
  const float* b3   = (const float*)d_in[7];
  const float* Wo   = (const float*)d_in[8];
  const float* bo   = (const float*)d_in[9];
  float* out = (float*)d_out;
  unsigned short* wsb = (unsigned short*)d_ws;

  const int N = in_sizes[0] / XC;                 // 131072
  const int nfragX = (N/16) * KQ1;                // 24576 fragments
  const size_t wbytes = (size_t)WTOT * 2;         // 2,555,904
  const size_t xbytes = (size_t)nfragX * 512 * 2; // 25,165,824

  convert_weights<<<dim3((WTOT + 255) / 256), dim3(256), 0, stream>>>(W1, W2, W3, Wo, wsb);

  if (ws_size >= wbytes + xbytes) {
    unsigned short* xsb2 = wsb + WTOT;
    convert_x<<<dim3((nfragX*512 + 255) / 256), dim3(256), 0, stream>>>(x, xsb2, nfragX);
    meganerf_fused<true><<<dim3(N / MT), dim3(NTHREADS), 0, stream>>>(
        x, cent, b1, b2, b3, bo, wsb, xsb2, out);
  } else {
    meganerf_fused<false><<<dim3(N / MT), dim3(NTHREADS), 0, stream>>>(
        x, cent, b1, b2, b3, bo, wsb, wsb, out);
  }
}